// Round 4
// baseline (214.278 us; speedup 1.0000x reference)
//
#include <hip/hip_runtime.h>

typedef float f32x4 __attribute__((ext_vector_type(4)));
typedef __bf16 bf16x8 __attribute__((ext_vector_type(8)));
typedef unsigned short u16x4 __attribute__((ext_vector_type(4)));

__device__ __forceinline__ unsigned short f2bf(float f) {
  union { float f; unsigned int u; } v; v.f = f;
  unsigned int r = (v.u + 0x7FFFu + ((v.u >> 16) & 1u)) >> 16;
  return (unsigned short)r;
}
__device__ __forceinline__ float bf2f(unsigned short h) {
  union { unsigned int u; float f; } v; v.u = ((unsigned int)h) << 16;
  return v.f;
}
__device__ __forceinline__ void gload_lds16(const void* g, void* l) {
  __builtin_amdgcn_global_load_lds(
      (const __attribute__((address_space(1))) unsigned int*)g,
      (__attribute__((address_space(3))) unsigned int*)l, 16, 0, 0);
}

// ---------------- prep: fp32->bf16 casts (all 3 arrays) + RoPE cos/sin table
__global__ __launch_bounds__(256) void prep_kernel(
    const float* __restrict__ x, const float* __restrict__ wqkv,
    const float* __restrict__ wout, unsigned short* __restrict__ xb,
    unsigned short* __restrict__ wqkvb, unsigned short* __restrict__ woutb,
    float2* __restrict__ tab) {
  const int N1 = 1048576, N2 = 786432, N3 = 262144;  // float4 counts
  int idx = blockIdx.x * 256 + threadIdx.x;
  if (idx < N1 + N2 + N3) {
    const float* src; unsigned short* dst; int i = idx;
    if (i < N1)           { src = x;    dst = xb; }
    else if (i < N1 + N2) { i -= N1;      src = wqkv; dst = wqkvb; }
    else                  { i -= N1 + N2; src = wout; dst = woutb; }
    float4 v = ((const float4*)src)[i];
    u16x4 o;
    o.x = f2bf(v.x); o.y = f2bf(v.y); o.z = f2bf(v.z); o.w = f2bf(v.w);
    ((u16x4*)dst)[i] = o;
  } else {
    int i = idx - (N1 + N2 + N3);
    if (i < 65536) {  // 2048 positions x 32 pairs
      int t = i >> 5, p = i & 31;
      float theta = exp2f(-(float)p * 0.4152410118609203f);  // log2(1e4)/32
      float sn, cs;
      sincosf((float)t * theta, &sn, &cs);
      tab[i] = make_float2(cs, sn);
    }
  }
}

// ---------------- GEMM1: qkv = x * Wqkv^T with fused RoPE epilogue ---------
// BM=128, BN=256, BK=64. 512 threads = 8 waves (2M x 4N), per-wave 64x64.
// Triple-buffered LDS (144 KB), 2-tile prefetch, counted vmcnt(12).
// LDS rows are 128 B -> XOR-swizzle 16B-block index with (row&7); the
// global SOURCE address is pre-swizzled (global_load_lds dest must be linear).
#define G1_SLOT ((128 + 256) * 64)  // elems per slot (A then B)

__global__ __launch_bounds__(512, 1) void gemm1_qkv(
    const unsigned short* __restrict__ A,   // x bf16 [4096][1024]
    const unsigned short* __restrict__ B,   // Wqkv bf16 [3072][1024]
    unsigned short* __restrict__ Cq,        // qkv bf16 [4096][3072]
    const float2* __restrict__ tab) {
  __shared__ unsigned short lds[3 * G1_SLOT];  // 144 KB
  const int K = 1024, NJ = 3072, NT = 16;      // NT = K/64
  const int tid = threadIdx.x;
  const int bm = blockIdx.y * 128, bn = blockIdx.x * 256;
  const int lane = tid & 63, w = tid >> 6, wr = w >> 2, wc = w & 3;
  const int rq = lane & 15, hi = lane >> 4;

  auto stage = [&](int slot, int kt) {
    unsigned short* s = lds + slot * G1_SLOT;
#pragma unroll
    for (int p = 0; p < 2; ++p) {  // A: 128x64 = 1024 chunks of 16B
      int ch = tid + p * 512;
      int row = ch >> 3, blk = (ch & 7) ^ (row & 7);
      gload_lds16(A + (size_t)(bm + row) * K + kt + blk * 8, s + ch * 8);
    }
#pragma unroll
    for (int p = 0; p < 4; ++p) {  // B: 256x64 = 2048 chunks
      int ch = tid + p * 512;
      int row = ch >> 3, blk = (ch & 7) ^ (row & 7);
      gload_lds16(B + (size_t)(bn + row) * K + kt + blk * 8,
                  s + 128 * 64 + ch * 8);
    }
  };

  f32x4 acc[4][4] = {};
  auto compute = [&](int slot) {
    const unsigned short* sA = lds + slot * G1_SLOT;
    const unsigned short* sB = sA + 128 * 64;
#pragma unroll
    for (int k = 0; k < 2; ++k) {
      bf16x8 fa[4], fb[4];
#pragma unroll
      for (int m = 0; m < 4; ++m) {
        int r = wr * 64 + m * 16 + rq;
        int b = (hi + k * 4) ^ (r & 7);
        fa[m] = *(const bf16x8*)(sA + r * 64 + b * 8);
      }
#pragma unroll
      for (int n = 0; n < 4; ++n) {
        int r = wc * 64 + n * 16 + rq;
        int b = (hi + k * 4) ^ (r & 7);
        fb[n] = *(const bf16x8*)(sB + r * 64 + b * 8);
      }
#pragma unroll
      for (int m = 0; m < 4; ++m)
#pragma unroll
        for (int n = 0; n < 4; ++n)
          acc[m][n] = __builtin_amdgcn_mfma_f32_16x16x32_bf16(fa[m], fb[n], acc[m][n], 0, 0, 0);
    }
  };

  stage(0, 0);
  stage(1, 64);
  for (int t = 0; t < NT; ++t) {
    asm volatile("s_waitcnt lgkmcnt(0)" ::: "memory");  // prior slot reads retired
    __builtin_amdgcn_s_barrier();                       // barrier A
    if (t + 2 < NT) stage((t + 2) % 3, (t + 2) * 64);
    if (t < NT - 2)
      asm volatile("s_waitcnt vmcnt(12)" ::: "memory");  // tile t's 6 loads done
    else if (t == NT - 2)
      asm volatile("s_waitcnt vmcnt(6)" ::: "memory");
    else
      asm volatile("s_waitcnt vmcnt(0)" ::: "memory");
    __builtin_amdgcn_s_barrier();                       // barrier B (publish)
    compute(t % 3);
  }

  // epilogue: RoPE on q,k column sections, then bf16 store
  const int r0 = bm + wr * 64 + hi * 4;
  const int c0 = bn + wc * 64 + rq;
#pragma unroll
  for (int m = 0; m < 4; ++m)
#pragma unroll
    for (int n = 0; n < 4; ++n) {
      int col = c0 + n * 16;
      int cw = col % 192;            // within-head offset: q<64, k<128, v>=128
      bool dorot = cw < 128;
      int p = (cw & 63) >> 1;
#pragma unroll
      for (int j = 0; j < 4; ++j) {
        int row = r0 + m * 16 + j;
        float val = acc[m][n][j];
        float part = __shfl_xor(val, 1);   // pair partner (adjacent column)
        float outv = val;
        if (dorot) {
          float2 cssn = tab[(row & 2047) * 32 + p];
          outv = (col & 1) ? (part * cssn.y + val * cssn.x)    // x1*sin + x2*cos
                           : (val * cssn.x - part * cssn.y);   // x1*cos - x2*sin
        }
        Cq[(size_t)row * NJ + col] = f2bf(outv);
      }
    }
}

// ---------------- bf16 GEMM, C = A * B^T (kept for out-proj) ---------------
template <bool OUTBF16>
__global__ __launch_bounds__(256) void gemm_bt(const unsigned short* __restrict__ A,
                                               const unsigned short* __restrict__ B,
                                               void* __restrict__ C,
                                               int M, int N, int K) {
  __shared__ unsigned short As[128][32];
  __shared__ unsigned short Bs[128][32];
  const int tid = threadIdx.x;
  const int lane = tid & 63;
  const int w = tid >> 6, wr = w >> 1, wc = w & 1;
  const int bm = blockIdx.y * 128, bn = blockIdx.x * 128;
  const int t4 = tid >> 2, c8 = (tid & 3) * 8;
  const unsigned short* Ab = A + (size_t)(bm + t4) * K + c8;
  const unsigned short* Bb = B + (size_t)(bn + t4) * K + c8;
  const int rq = lane & 15, kg = (lane >> 4) * 8;
  f32x4 acc[4][4] = {};
  for (int kt = 0; kt < K; kt += 32) {
    gload_lds16(Ab + kt,                  &As[t4][c8]);
    gload_lds16(Ab + kt + (size_t)64 * K, &As[t4 + 64][c8]);
    gload_lds16(Bb + kt,                  &Bs[t4][c8]);
    gload_lds16(Bb + kt + (size_t)64 * K, &Bs[t4 + 64][c8]);
    __syncthreads();
    bf16x8 fa[4], fb[4];
#pragma unroll
    for (int m = 0; m < 4; ++m) fa[m] = *(const bf16x8*)&As[wr * 64 + m * 16 + rq][kg];
#pragma unroll
    for (int n = 0; n < 4; ++n) fb[n] = *(const bf16x8*)&Bs[wc * 64 + n * 16 + rq][kg];
#pragma unroll
    for (int m = 0; m < 4; ++m)
#pragma unroll
      for (int n = 0; n < 4; ++n)
        acc[m][n] = __builtin_amdgcn_mfma_f32_16x16x32_bf16(fa[m], fb[n], acc[m][n], 0, 0, 0);
    __syncthreads();
  }
  const int r0 = bm + wr * 64 + (lane >> 4) * 4;
  const int c0 = bn + wc * 64 + rq;
#pragma unroll
  for (int m = 0; m < 4; ++m)
#pragma unroll
    for (int n = 0; n < 4; ++n)
#pragma unroll
      for (int j = 0; j < 4; ++j) {
        int row = r0 + m * 16 + j, col = c0 + n * 16;
        if (OUTBF16)
          ((unsigned short*)C)[(size_t)row * N + col] = f2bf(acc[m][n][j]);
        else
          ((float*)C)[(size_t)row * N + col] = acc[m][n][j];
      }
}

// ---------------- sliding-window attention (unchanged) ---------------------
#define WMAX 256
__global__ __launch_bounds__(256) void attn_kernel(const unsigned short* __restrict__ qkv,
                                                   unsigned short* __restrict__ attnb,
                                                   const int* __restrict__ winp) {
  __shared__ unsigned short Qs[64][72];
  __shared__ unsigned short KPs[320 * 72];
  __shared__ unsigned short Vt[64][328];
  const int T = 2048;
  const int tid = threadIdx.x;
  const int bid = blockIdx.x;
  const int qt = bid & 31;
  const int bh = bid >> 5;
  const int b = bh >> 4, h = bh & 15;
  const int qbase = qt * 64;
  const int kbase = qbase - WMAX;
  const int win = *winp;
  const unsigned short* base = qkv + (size_t)b * T * 3072 + h * 192;
  const int tr = tid >> 2, tc = (tid & 3) * 16;
  {
    const unsigned short* s = base + (size_t)(qbase + tr) * 3072 + tc;
    *(int4*)&Qs[tr][tc]     = *(const int4*)s;
    *(int4*)&Qs[tr][tc + 8] = *(const int4*)(s + 8);
  }
#pragma unroll
  for (int p5 = 0; p5 < 5; ++p5) {
    int s = p5 * 64 + tr;
    int j = kbase + s;
    int jc = j < 0 ? 0 : j;
    const unsigned short* sk = base + (size_t)jc * 3072 + 64 + tc;
    *(int4*)&KPs[s * 72 + tc]     = *(const int4*)sk;
    *(int4*)&KPs[s * 72 + tc + 8] = *(const int4*)(sk + 8);
    const unsigned short* sv = base + (size_t)jc * 3072 + 128 + tc;
    unsigned short tmp[16];
    *(int4*)&tmp[0] = *(const int4*)sv;
    *(int4*)&tmp[8] = *(const int4*)(sv + 8);
#pragma unroll
    for (int e = 0; e < 16; ++e) Vt[tc + e][s] = tmp[e];
  }
  __syncthreads();
  const int lane = tid & 63, wv = tid >> 6;
  const int rbase = wv * 16;
  const int rq = lane & 15, kg = (lane >> 4) * 8;
  bf16x8 qa[2];
#pragma unroll
  for (int kk = 0; kk < 2; ++kk)
    qa[kk] = *(const bf16x8*)&Qs[rbase + rq][kk * 32 + kg];
  float sc[20][4];
#pragma unroll
  for (int n = 0; n < 20; ++n) {
    f32x4 s = {};
#pragma unroll
    for (int kk = 0; kk < 2; ++kk) {
      bf16x8 kb = *(const bf16x8*)&KPs[(n * 16 + rq) * 72 + kk * 32 + kg];
      s = __builtin_amdgcn_mfma_f32_16x16x32_bf16(qa[kk], kb, s, 0, 0, 0);
    }
#pragma unroll
    for (int r = 0; r < 4; ++r) sc[n][r] = s[r];
  }
  const float scale = 0.125f;
#pragma unroll
  for (int r = 0; r < 4; ++r) {
    const int i = qbase + rbase + (lane >> 4) * 4 + r;
    float mx = -1e30f;
#pragma unroll
    for (int n = 0; n < 20; ++n) {
      int j = kbase + n * 16 + rq;
      bool valid = (j >= 0) && (j <= i) && (i - j <= win);
      float v = valid ? sc[n][r] * scale : -1e30f;
      sc[n][r] = v;
      mx = fmaxf(mx, v);
    }
#pragma unroll
    for (int off = 1; off < 16; off <<= 1) mx = fmaxf(mx, __shfl_xor(mx, off));
    float sum = 0.f;
#pragma unroll
    for (int n = 0; n < 20; ++n) {
      float pv = __expf(sc[n][r] - mx);
      sc[n][r] = pv;
      sum += pv;
    }
#pragma unroll
    for (int off = 1; off < 16; off <<= 1) sum += __shfl_xor(sum, off);
    float inv = 1.0f / sum;
#pragma unroll
    for (int n = 0; n < 20; ++n) sc[n][r] *= inv;
  }
  __syncthreads();
#pragma unroll
  for (int n = 0; n < 20; ++n)
#pragma unroll
    for (int r = 0; r < 4; ++r)
      KPs[(rbase + (lane >> 4) * 4 + r) * 328 + n * 16 + rq] = f2bf(sc[n][r]);
  f32x4 oacc[4] = {};
#pragma unroll
  for (int kk = 0; kk < 10; ++kk) {
    bf16x8 pa = *(const bf16x8*)&KPs[(rbase + rq) * 328 + kk * 32 + kg];
#pragma unroll
    for (int n = 0; n < 4; ++n) {
      bf16x8 vb = *(const bf16x8*)&Vt[n * 16 + rq][kk * 32 + kg];
      oacc[n] = __builtin_amdgcn_mfma_f32_16x16x32_bf16(pa, vb, oacc[n], 0, 0, 0);
    }
  }
#pragma unroll
  for (int n = 0; n < 4; ++n)
#pragma unroll
    for (int j = 0; j < 4; ++j) {
      int r = qbase + rbase + (lane >> 4) * 4 + j;
      int d = n * 16 + rq;
      attnb[(size_t)(b * T + r) * 1024 + h * 64 + d] = f2bf(oacc[n][j]);
    }
}

// ---------------- launch ----------------------------------------------------
extern "C" void kernel_launch(void* const* d_in, const int* in_sizes, int n_in,
                              void* d_out, int out_size, void* d_ws, size_t ws_size,
                              hipStream_t stream) {
  const float* x    = (const float*)d_in[0];
  const float* Wqkv = (const float*)d_in[1];
  const float* Wout = (const float*)d_in[2];
  const int*   winp = (const int*)d_in[3];

  const int M = 4096, C = 1024, N1 = 3072;
  unsigned short* xb    = (unsigned short*)d_ws;
  unsigned short* wqkvb = xb    + (size_t)M * C;
  unsigned short* woutb = wqkvb + (size_t)N1 * C;
  unsigned short* qkvb  = woutb + (size_t)C * C;
  unsigned short* attnb = qkvb  + (size_t)M * N1;
  float2*         tab   = (float2*)(attnb + (size_t)M * C);  // 2048*32 float2

  const int PREP = 1048576 + 786432 + 262144 + 65536;
  prep_kernel<<<(PREP + 255) / 256, 256, 0, stream>>>(x, Wqkv, Wout, xb, wqkvb,
                                                      woutb, tab);

  gemm1_qkv<<<dim3(12, 32), 512, 0, stream>>>(xb, wqkvb, qkvb, tab);

  attn_kernel<<<2 * 16 * 32, 256, 0, stream>>>(qkvb, attnb, winp);

  dim3 g2(C / 128, M / 128);
  gemm_bt<false><<<g2, 256, 0, stream>>>(attnb, woutb, (float*)d_out, M, C, C);
}